// Round 2
// baseline (523.385 us; speedup 1.0000x reference)
//
#include <hip/hip_runtime.h>

typedef unsigned short u16;
typedef __attribute__((ext_vector_type(8))) unsigned short u16x8;
typedef __attribute__((ext_vector_type(8))) short s16x8;
typedef __attribute__((ext_vector_type(4))) float f32x4;

__device__ __forceinline__ float bf2f(u16 u){
  union { unsigned int i; float f; } v; v.i = ((unsigned int)u) << 16; return v.f;
}
__device__ __forceinline__ u16 f2bf(float f){
  union { float f; unsigned int i; } v; v.f = f;
  unsigned int r = v.i + 0x7fffu + ((v.i >> 16) & 1u);   // round-nearest-even
  return (u16)(r >> 16);
}

// ---------------------------------------------------------------------------
// cast fp32 -> bf16 (weight prep)
// ---------------------------------------------------------------------------
__global__ __launch_bounds__(256) void cast_bf16(
    const float* __restrict__ src, u16* __restrict__ dst, int n)
{
  const int i = blockIdx.x * 256 + threadIdx.x;
  if (i < n) dst[i] = f2bf(src[i]);
}

// ---------------------------------------------------------------------------
// K0: transpose fe [B,64,E] (fp32) -> feT [B,E,64] (bf16)
// ---------------------------------------------------------------------------
__global__ __launch_bounds__(256) void transpose64(
    const float* __restrict__ x, u16* __restrict__ xT, int E)
{
  __shared__ u16 tile[64][66];
  const int b   = blockIdx.z;
  const int e0  = blockIdx.x * 64;
  const int col = threadIdx.x & 63;
  const int r   = threadIdx.x >> 6;
  const int e   = e0 + col;
  #pragma unroll
  for (int k = 0; k < 16; k++) {
    const int c = r * 16 + k;
    float v = 0.f;
    if (e < E) v = x[((size_t)b * 64 + c) * (size_t)E + e];
    tile[c][col] = f2bf(v);
  }
  __syncthreads();
  const int e_l  = threadIdx.x >> 2;
  const int part = threadIdx.x & 3;
  const int eg   = e0 + e_l;
  if (eg < E) {
    u16* dst = xT + ((size_t)b * E + eg) * 64 + part * 16;
    #pragma unroll
    for (int h = 0; h < 2; h++) {
      u16x8 v;
      #pragma unroll
      for (int cc = 0; cc < 8; cc++) v[cc] = tile[part * 16 + h * 8 + cc][e_l];
      *(u16x8*)(dst + h * 8) = v;
    }
  }
}

// ---------------------------------------------------------------------------
// Conv: y[b,o,e] = sum_{c,s} W[o, c*5+s] * Gm[s,c,e] + bias[o]  (pre-norm)
// xT: [B,E,CIN] bf16, gidx: [B,E,4] int32, W: [128, CIN*5] bf16,
// bias: [128] fp32, y: [B,128,E] fp32.
// One block = 32 edges, all 128 output channels. 256 thr = 4 waves.
// ---------------------------------------------------------------------------
template <int CIN>
__global__ __launch_bounds__(256) void conv_mfma(
    const u16* __restrict__ xT, const int* __restrict__ gidx,
    const u16* __restrict__ W, const float* __restrict__ bias,
    float* __restrict__ y, int E)
{
  constexpr int KK  = CIN * 5;
  constexpr int LDF = KK + 8;          // +16B pad per row
  constexpr int NV  = CIN / 64;        // 8-channel chunks per sub-thread
  __shared__ __align__(16) u16 F[32 * LDF];   // [edge][k], k = c*5+s

  const int b   = blockIdx.z;
  const int t   = threadIdx.x;
  const int e_l = t >> 3;              // 0..31
  const int sub = t & 7;               // 0..7
  const size_t e_raw = (size_t)blockIdx.x * 32 + e_l;
  const int e = (int)(e_raw < (size_t)E ? e_raw : (size_t)(E - 1));

  // --- staging: gather 5 neighbor rows, build symmetric features into LDS ---
  int rows[5];
  {
    const int4 g = *(const int4*)(gidx + ((size_t)b * E + e) * 4);
    rows[0] = e; rows[1] = g.x; rows[2] = g.y; rows[3] = g.z; rows[4] = g.w;
  }
  const u16* base = xT + (size_t)b * E * CIN;
  #pragma unroll
  for (int v = 0; v < NV; v++) {
    const int c0 = (sub * NV + v) * 8;
    float f[5][8];
    #pragma unroll
    for (int j = 0; j < 5; j++) {
      u16x8 u = *(const u16x8*)(base + (size_t)rows[j] * CIN + c0);
      #pragma unroll
      for (int c = 0; c < 8; c++) f[j][c] = bf2f(u[c]);
    }
    u16* dst = &F[e_l * LDF + c0 * 5];
    #pragma unroll
    for (int c = 0; c < 8; c++) {
      const float a1 = f[1][c], a2 = f[2][c], a3 = f[3][c], a4 = f[4][c];
      dst[c * 5 + 0] = f2bf(f[0][c]);
      dst[c * 5 + 1] = f2bf(a1 + a3);
      dst[c * 5 + 2] = f2bf(a2 + a4);
      dst[c * 5 + 3] = f2bf(fabsf(a1 - a3));
      dst[c * 5 + 4] = f2bf(fabsf(a2 - a4));
    }
  }
  __syncthreads();

  // --- MFMA: wave wv covers out rows [wv*32, wv*32+32), 2 n-tiles of 16 ---
  const int lane = t & 63, wv = t >> 6;
  const int lr = lane & 15, quad = lane >> 4;
  f32x4 acc[2][2] = {{{0.f,0.f,0.f,0.f},{0.f,0.f,0.f,0.f}},
                     {{0.f,0.f,0.f,0.f},{0.f,0.f,0.f,0.f}}};
  #pragma unroll
  for (int kt = 0; kt < KK / 32; kt++) {
    const int koff = kt * 32 + quad * 8;
    s16x8 a0 = *(const s16x8*)(W + (size_t)(wv * 32 + lr) * KK + koff);
    s16x8 a1 = *(const s16x8*)(W + (size_t)(wv * 32 + 16 + lr) * KK + koff);
    s16x8 b0 = *(const s16x8*)&F[lr * LDF + koff];
    s16x8 b1 = *(const s16x8*)&F[(16 + lr) * LDF + koff];
    acc[0][0] = __builtin_amdgcn_mfma_f32_16x16x32_bf16(a0, b0, acc[0][0], 0, 0, 0);
    acc[0][1] = __builtin_amdgcn_mfma_f32_16x16x32_bf16(a0, b1, acc[0][1], 0, 0, 0);
    acc[1][0] = __builtin_amdgcn_mfma_f32_16x16x32_bf16(a1, b0, acc[1][0], 0, 0, 0);
    acc[1][1] = __builtin_amdgcn_mfma_f32_16x16x32_bf16(a1, b1, acc[1][1], 0, 0, 0);
  }
  // --- epilogue: D[row=quad*4+r][col=lr], add bias, store fp32 ---
  #pragma unroll
  for (int i = 0; i < 2; i++) {
    #pragma unroll
    for (int j = 0; j < 2; j++) {
      #pragma unroll
      for (int r = 0; r < 4; r++) {
        const int m = wv * 32 + i * 16 + quad * 4 + r;
        const size_t eg = (size_t)blockIdx.x * 32 + j * 16 + lr;
        if (eg < (size_t)E)
          y[((size_t)b * 128 + m) * E + eg] = acc[i][j][r] + bias[m];
      }
    }
  }
}

// ---------------------------------------------------------------------------
// Row stats: one block per (b,o) row -> (mean, rsqrt(var+eps))
// ---------------------------------------------------------------------------
__global__ __launch_bounds__(256) void row_stats(
    const float* __restrict__ y, float2* __restrict__ stats, int E)
{
  const int row = blockIdx.x;
  const float* p = y + (size_t)row * E;
  float s = 0.f, s2 = 0.f;
  const int n4 = E >> 2;
  const float4* p4 = (const float4*)p;
  for (int i = threadIdx.x; i < n4; i += 256) {
    float4 v = p4[i];
    s  += v.x + v.y + v.z + v.w;
    s2 += v.x * v.x + v.y * v.y + v.z * v.z + v.w * v.w;
  }
  for (int i = n4 * 4 + threadIdx.x; i < E; i += 256) {
    float v = p[i]; s += v; s2 += v * v;
  }
  #pragma unroll
  for (int off = 32; off > 0; off >>= 1) {
    s  += __shfl_down(s, off);
    s2 += __shfl_down(s2, off);
  }
  __shared__ float rs[4], rs2[4];
  const int wv = threadIdx.x >> 6;
  if ((threadIdx.x & 63) == 0) { rs[wv] = s; rs2[wv] = s2; }
  __syncthreads();
  if (threadIdx.x == 0) {
    s = rs[0] + rs[1] + rs[2] + rs[3];
    s2 = rs2[0] + rs2[1] + rs2[2] + rs2[3];
    const float mean = s / E;
    const float var  = s2 / E - mean * mean;
    stats[row] = make_float2(mean, rsqrtf(var + 1e-5f));
  }
}

// ---------------------------------------------------------------------------
// Normalize + relu; write x1n [B,128,E] bf16 and transposed x1T [B,E,128] bf16
// Block tile: 32 channels x 64 edges.
// ---------------------------------------------------------------------------
__global__ __launch_bounds__(256) void norm_relu_tr(
    const float* __restrict__ y, const float2* __restrict__ stats,
    u16* __restrict__ xn, u16* __restrict__ xT, int E)
{
  __shared__ u16 tile[32][66];
  const int b  = blockIdx.z;
  const int o0 = blockIdx.y * 32;
  const int e0 = blockIdx.x * 64;
  const int col = threadIdx.x & 63;
  const int r   = threadIdx.x >> 6;
  const int e   = e0 + col;
  #pragma unroll
  for (int k = 0; k < 8; k++) {
    const int ol = r * 8 + k;
    const int o  = o0 + ol;
    const float2 st = stats[b * 128 + o];
    float v = 0.f;
    if (e < E) v = y[((size_t)b * 128 + o) * E + e];
    float xv = (v - st.x) * st.y;
    if (xv < 0.f) xv = 0.f;
    const u16 u = f2bf(xv);
    if (e < E) xn[((size_t)b * 128 + o) * E + e] = u;
    tile[ol][col] = u;
  }
  __syncthreads();
  const int e_l  = threadIdx.x >> 2;
  const int part = threadIdx.x & 3;
  const int eg   = e0 + e_l;
  if (eg < E) {
    u16x8 v;
    #pragma unroll
    for (int cc = 0; cc < 8; cc++) v[cc] = tile[part * 8 + cc][e_l];
    *(u16x8*)(xT + ((size_t)b * E + eg) * 128 + o0 + part * 8) = v;
  }
}

// ---------------------------------------------------------------------------
// Final: out = relu( (y2 - m)*rstd + x1n ), fp32
// ---------------------------------------------------------------------------
__global__ __launch_bounds__(256) void final_k(
    const float* __restrict__ y, const float2* __restrict__ stats,
    const u16* __restrict__ xn, float* __restrict__ out, int E)
{
  const int b = blockIdx.z, o = blockIdx.y;
  const int e = blockIdx.x * 256 + threadIdx.x;
  if (e >= E) return;
  const float2 st = stats[b * 128 + o];
  const size_t idx = ((size_t)b * 128 + o) * E + e;
  float v = (y[idx] - st.x) * st.y + bf2f(xn[idx]);
  out[idx] = v < 0.f ? 0.f : v;
}

// ---------------------------------------------------------------------------
extern "C" void kernel_launch(void* const* d_in, const int* in_sizes, int n_in,
                              void* d_out, int out_size, void* d_ws, size_t ws_size,
                              hipStream_t stream)
{
  const float* fe  = (const float*)d_in[0];
  const int*   gmm = (const int*)d_in[1];
  const float* w1  = (const float*)d_in[2];
  const float* b1  = (const float*)d_in[3];
  const float* w2  = (const float*)d_in[4];
  const float* b2  = (const float*)d_in[5];
  float* out = (float*)d_out;

  const int B = 2, CIN = 64, COUT = 128;
  const int E = in_sizes[0] / (B * CIN);   // 100000

  // workspace layout (feT aliased with x1n: feT dead before x1n written)
  char* p = (char*)d_ws;
  auto alloc = [&](size_t bytes) -> char* {
    char* q = p; p += (bytes + 255) & ~(size_t)255; return q;
  };
  const size_t feT_b = (size_t)B * E * CIN * 2;
  const size_t x1n_b = (size_t)B * COUT * E * 2;
  char* regA = alloc(x1n_b > feT_b ? x1n_b : feT_b);
  u16*   feT = (u16*)regA;
  u16*   x1n = (u16*)regA;
  u16*   x1T = (u16*)alloc((size_t)B * E * COUT * 2);
  float* y   = (float*)alloc((size_t)B * COUT * E * 4);
  float2* stats = (float2*)alloc((size_t)B * COUT * sizeof(float2));
  u16* w1b = (u16*)alloc((size_t)COUT * CIN * 5 * 2);
  u16* w2b = (u16*)alloc((size_t)COUT * COUT * 5 * 2);

  const int n_w1 = COUT * CIN * 5, n_w2 = COUT * COUT * 5;
  cast_bf16 <<<dim3((n_w1 + 255) / 256), 256, 0, stream>>>(w1, w1b, n_w1);
  cast_bf16 <<<dim3((n_w2 + 255) / 256), 256, 0, stream>>>(w2, w2b, n_w2);

  transpose64 <<<dim3((E + 63) / 64, 1, B), 256, 0, stream>>>(fe, feT, E);
  conv_mfma<64> <<<dim3((E + 31) / 32, 1, B), 256, 0, stream>>>(feT, gmm, w1b, b1, y, E);
  row_stats <<<dim3(B * COUT), 256, 0, stream>>>(y, stats, E);
  norm_relu_tr <<<dim3((E + 63) / 64, COUT / 32, B), 256, 0, stream>>>(y, stats, x1n, x1T, E);
  conv_mfma<128> <<<dim3((E + 31) / 32, 1, B), 256, 0, stream>>>(x1T, gmm, w2b, b2, y, E);
  row_stats <<<dim3(B * COUT), 256, 0, stream>>>(y, stats, E);
  final_k <<<dim3((E + 255) / 256, COUT, B), 256, 0, stream>>>(y, stats, x1n, out, E);
}